// Round 1
// baseline (8489.809 us; speedup 1.0000x reference)
//
#include <hip/hip_runtime.h>

// Graph_NN: 3-layer SAGE (gcn aggregator) on N=100000 nodes, E=1600000 edges, D=128.
//   h = emb[annotation]; inv = 1/(indeg+1)
//   for l in 0..2: agg = segsum(h[src], dst); h = relu(((h+agg)*inv) @ W[l] + b[l])
// All fp32 (no fp32 MFMA on CDNA4; bf16 MFMA precision too risky vs 1.27e-4 absmax).

#define D 128
#define L 3

// ---- degree count (fp32 atomic add of 1.0 is exact below 2^24) ----
__global__ void k_deg(const int* __restrict__ dst, float* __restrict__ deg, int E) {
    int e = blockIdx.x * blockDim.x + threadIdx.x;
    if (e < E) atomicAdd(&deg[dst[e]], 1.0f);
}

__global__ void k_inv(float* __restrict__ deg, int n) {
    int i = blockIdx.x * blockDim.x + threadIdx.x;
    if (i < n) deg[i] = 1.0f / (deg[i] + 1.0f);
}

// ---- h0 = emb[annotation], float4-vectorized (32 float4 per row) ----
__global__ void k_gather(const int* __restrict__ ann, const float4* __restrict__ emb,
                         float4* __restrict__ h, int n) {
    int t = blockIdx.x * blockDim.x + threadIdx.x;
    if (t >= n * 32) return;
    int i = t >> 5, c = t & 31;
    h[i * 32 + c] = emb[ann[i] * 32 + c];
}

// ---- agg[dst] += h[src]: 32 threads/edge, float4 read + 4 scalar fp32 atomics ----
__global__ void k_scatter(const int* __restrict__ src, const int* __restrict__ dst,
                          const float4* __restrict__ h, float* __restrict__ agg, int E) {
    int t = blockIdx.x * blockDim.x + threadIdx.x;   // E*32 = 51.2M < 2^31
    if (t >= E * 32) return;
    int e = t >> 5, c = t & 31;
    int s = src[e], d = dst[e];
    float4 v = h[s * 32 + c];
    float* a = agg + d * D + c * 4;
    atomicAdd(a + 0, v.x);
    atomicAdd(a + 1, v.y);
    atomicAdd(a + 2, v.z);
    atomicAdd(a + 3, v.w);
}

// ---- out = relu(((hin+agg)*inv) @ W + b), 32 rows per block, W staged in LDS ----
// LDS: W 64KB + X^T tile 18KB = 82.4KB -> 1 block/CU. Compute-ish bound; fine for now.
__global__ __launch_bounds__(256) void k_gemm(
    const float* __restrict__ hin, const float* __restrict__ agg,
    const float* __restrict__ inv, const float* __restrict__ W,
    const float* __restrict__ bias, float* __restrict__ out) {
    __shared__ float Wl[128 * 128];
    __shared__ float Xs[128 * 36];   // X transposed: Xs[k*36 + r], stride 36 (pad 4, keeps 16B align)
    int tid = threadIdx.x;
    int row0 = blockIdx.x * 32;

    // stage W (16384 floats) cooperatively as float4
    const float4* W4 = (const float4*)W;
    float4* Wl4 = (float4*)Wl;
    #pragma unroll
    for (int i = 0; i < 16; i++) Wl4[tid + i * 256] = W4[tid + i * 256];

    // stage X tile: x[r][k] = (h[r][k]+agg[r][k])*inv[r], stored transposed
    {
        int r = tid >> 3;            // 0..31 (row within tile)
        int qb = tid & 7;            // 0..7  (float4 chunk base)
        int grow = row0 + r;
        float s = inv[grow];
        const float4* h4 = (const float4*)hin;
        const float4* a4 = (const float4*)agg;
        #pragma unroll
        for (int j = 0; j < 4; j++) {
            int q = qb + j * 8;      // 0..31
            float4 hv = h4[grow * 32 + q];
            float4 av = a4[grow * 32 + q];
            Xs[(q * 4 + 0) * 36 + r] = (hv.x + av.x) * s;
            Xs[(q * 4 + 1) * 36 + r] = (hv.y + av.y) * s;
            Xs[(q * 4 + 2) * 36 + r] = (hv.z + av.z) * s;
            Xs[(q * 4 + 3) * 36 + r] = (hv.w + av.w) * s;
        }
    }
    __syncthreads();

    // each thread: 4 rows x 4 cols micro-tile
    float acc[4][4] = {};
    int r0 = (tid >> 5) * 4;         // 0,4,..,28
    int c0 = (tid & 31) * 4;         // 0,4,..,124
    #pragma unroll 4
    for (int k = 0; k < 128; k++) {
        float4 xv = *(const float4*)&Xs[k * 36 + r0];
        float4 wv = *(const float4*)&Wl[k * 128 + c0];
        acc[0][0] += xv.x * wv.x; acc[0][1] += xv.x * wv.y; acc[0][2] += xv.x * wv.z; acc[0][3] += xv.x * wv.w;
        acc[1][0] += xv.y * wv.x; acc[1][1] += xv.y * wv.y; acc[1][2] += xv.y * wv.z; acc[1][3] += xv.y * wv.w;
        acc[2][0] += xv.z * wv.x; acc[2][1] += xv.z * wv.y; acc[2][2] += xv.z * wv.z; acc[2][3] += xv.z * wv.w;
        acc[3][0] += xv.w * wv.x; acc[3][1] += xv.w * wv.y; acc[3][2] += xv.w * wv.z; acc[3][3] += xv.w * wv.w;
    }

    float4 bv = *(const float4*)&bias[c0];
    #pragma unroll
    for (int i = 0; i < 4; i++) {
        int r = row0 + r0 + i;
        float4 o;
        o.x = fmaxf(acc[i][0] + bv.x, 0.0f);
        o.y = fmaxf(acc[i][1] + bv.y, 0.0f);
        o.z = fmaxf(acc[i][2] + bv.z, 0.0f);
        o.w = fmaxf(acc[i][3] + bv.w, 0.0f);
        *(float4*)&out[r * 128 + c0] = o;
    }
}

extern "C" void kernel_launch(void* const* d_in, const int* in_sizes, int n_in,
                              void* d_out, int out_size, void* d_ws, size_t ws_size,
                              hipStream_t stream) {
    const int*   ann = (const int*)d_in[0];
    const int*   src = (const int*)d_in[1];
    const int*   dst = (const int*)d_in[2];
    const float* emb = (const float*)d_in[3];
    const float* Ws  = (const float*)d_in[4];
    const float* bs  = (const float*)d_in[5];
    float* out = (float*)d_out;

    const int N = in_sizes[0];   // 100000
    const int E = in_sizes[1];   // 1600000

    // ws layout (floats): [0, N) inv/deg ; [131072, +N*D) h_a ; then agg (N*D)
    // total ~103 MB
    float* inv = (float*)d_ws;
    float* h_a = (float*)d_ws + 131072;
    float* agg = h_a + (size_t)N * D;

    hipMemsetAsync(inv, 0, (size_t)N * sizeof(float), stream);
    k_deg<<<(E + 255) / 256, 256, 0, stream>>>(dst, inv, E);
    k_inv<<<(N + 255) / 256, 256, 0, stream>>>(inv, N);
    k_gather<<<(N * 32 + 255) / 256, 256, 0, stream>>>(ann, (const float4*)emb, (float4*)h_a, N);

    const float* hin = h_a;
    for (int l = 0; l < L; l++) {
        float* hout = (l & 1) ? h_a : out;   // l0: ws->out, l1: out->ws, l2: ws->out
        hipMemsetAsync(agg, 0, (size_t)N * D * sizeof(float), stream);
        k_scatter<<<(E * 32 + 255) / 256, 256, 0, stream>>>(src, dst, (const float4*)hin, agg, E);
        // N divisible by 32 (100000 = 3125*32)
        k_gemm<<<N / 32, 256, 0, stream>>>(hin, agg, inv, Ws + (size_t)l * D * D,
                                           bs + (size_t)l * D, hout);
        hin = hout;
    }
}

// Round 2
// 1020.103 us; speedup vs baseline: 8.3225x; 8.3225x over previous
//
#include <hip/hip_runtime.h>

// Graph_NN: 3-layer SAGE (gcn aggregator), N=100000, E=1600000, D=128, fp32.
// R2: replace fp32 atomic scatter (95% of runtime) with CSR build + per-node
// wave gather. CSR built once per launch; aggregation writes the scaled GEMM
// input x directly; GEMM runs in place on x (row-local, no cross-block hazard).

#define D 128
#define L 3

// ---------- CSR build ----------
__global__ void k_count(const int* __restrict__ dst, int* __restrict__ deg, int E) {
    int e = blockIdx.x * blockDim.x + threadIdx.x;
    if (e < E) atomicAdd(&deg[dst[e]], 1);
}

__global__ void k_bsum(const int* __restrict__ deg, int* __restrict__ bsum, int n) {
    __shared__ int s[256];
    int t = threadIdx.x, i = blockIdx.x * 256 + t;
    s[t] = (i < n) ? deg[i] : 0;
    __syncthreads();
    for (int off = 128; off > 0; off >>= 1) { if (t < off) s[t] += s[t + off]; __syncthreads(); }
    if (t == 0) bsum[blockIdx.x] = s[0];
}

// exclusive scan of bsum[0..nb) in one 512-thread block; also writes row_ptr[N]=E
__global__ void k_scanb(int* __restrict__ bsum, int nb, int* __restrict__ row_ptr, int N, int E) {
    __shared__ int s[512];
    int t = threadIdx.x;
    int v = (t < nb) ? bsum[t] : 0;
    s[t] = v;
    __syncthreads();
    for (int off = 1; off < 512; off <<= 1) {
        int x = (t >= off) ? s[t - off] : 0;
        __syncthreads();
        s[t] += x;
        __syncthreads();
    }
    if (t < nb) bsum[t] = s[t] - v;          // exclusive prefix
    if (t == 0) row_ptr[N] = E;
}

__global__ void k_scan_local(const int* __restrict__ deg, const int* __restrict__ bpre,
                             int* __restrict__ row_ptr, int n) {
    __shared__ int s[256];
    int t = threadIdx.x, i = blockIdx.x * 256 + t;
    int v = (i < n) ? deg[i] : 0;
    s[t] = v;
    __syncthreads();
    for (int off = 1; off < 256; off <<= 1) {
        int x = (t >= off) ? s[t - off] : 0;
        __syncthreads();
        s[t] += x;
        __syncthreads();
    }
    if (i < n) row_ptr[i] = bpre[blockIdx.x] + s[t] - v;   // exclusive
}

__global__ void k_fill(const int* __restrict__ src, const int* __restrict__ dst,
                       const int* __restrict__ row_ptr, int* __restrict__ cur,
                       int* __restrict__ eidx, int E) {
    int e = blockIdx.x * blockDim.x + threadIdx.x;
    if (e >= E) return;
    int d = dst[e];
    int pos = atomicAdd(&cur[d], 1);
    eidx[row_ptr[d] + pos] = src[e];
}

// ---------- h0 = emb[annotation] ----------
__global__ void k_gather(const int* __restrict__ ann, const float4* __restrict__ emb,
                         float4* __restrict__ h, int n) {
    int t = blockIdx.x * blockDim.x + threadIdx.x;
    if (t >= n * 32) return;
    int i = t >> 5, c = t & 31;
    h[i * 32 + c] = emb[ann[i] * 32 + c];
}

// ---------- aggregation: one 64-lane wave per node ----------
// x[v] = (h[v] + sum_{u->v} h[u]) / (indeg(v)+1)
__global__ __launch_bounds__(256) void k_agg(
    const float2* __restrict__ h2, const int* __restrict__ row_ptr,
    const int* __restrict__ eidx, float2* __restrict__ x2, int n) {
    int v = blockIdx.x * 4 + (threadIdx.x >> 6);     // node; grid sized exactly
    int lane = threadIdx.x & 63;
    int beg = row_ptr[v], end = row_ptr[v + 1];      // wave-uniform
    float2 acc = h2[(size_t)v * 64 + lane];
    for (int e = beg; e < end; e++) {
        int s = eidx[e];                              // wave-uniform (scalar load)
        float2 w = h2[(size_t)s * 64 + lane];
        acc.x += w.x; acc.y += w.y;
    }
    float sc = 1.0f / (float)(end - beg + 1);
    x2[(size_t)v * 64 + lane] = make_float2(acc.x * sc, acc.y * sc);
}

// ---------- out = relu(x @ W + b), in place (x aliases out; row-local) ----------
__global__ __launch_bounds__(256) void k_gemm(
    const float* __restrict__ x, const float* __restrict__ W,
    const float* __restrict__ bias, float* __restrict__ out) {
    __shared__ float Wl[128 * 128];
    __shared__ float Xs[128 * 36];   // X^T tile: Xs[k*36 + r]
    int tid = threadIdx.x;
    int row0 = blockIdx.x * 32;

    const float4* W4 = (const float4*)W;
    float4* Wl4 = (float4*)Wl;
    #pragma unroll
    for (int i = 0; i < 16; i++) Wl4[tid + i * 256] = W4[tid + i * 256];

    {
        int r = tid >> 3;            // 0..31
        int qb = tid & 7;            // 0..7
        int grow = row0 + r;
        const float4* x4 = (const float4*)x;
        #pragma unroll
        for (int j = 0; j < 4; j++) {
            int q = qb + j * 8;      // 0..31
            float4 v = x4[(size_t)grow * 32 + q];
            Xs[(q * 4 + 0) * 36 + r] = v.x;
            Xs[(q * 4 + 1) * 36 + r] = v.y;
            Xs[(q * 4 + 2) * 36 + r] = v.z;
            Xs[(q * 4 + 3) * 36 + r] = v.w;
        }
    }
    __syncthreads();

    float acc[4][4] = {};
    int r0 = (tid >> 5) * 4;
    int c0 = (tid & 31) * 4;
    #pragma unroll 4
    for (int k = 0; k < 128; k++) {
        float4 xv = *(const float4*)&Xs[k * 36 + r0];
        float4 wv = *(const float4*)&Wl[k * 128 + c0];
        acc[0][0] += xv.x * wv.x; acc[0][1] += xv.x * wv.y; acc[0][2] += xv.x * wv.z; acc[0][3] += xv.x * wv.w;
        acc[1][0] += xv.y * wv.x; acc[1][1] += xv.y * wv.y; acc[1][2] += xv.y * wv.z; acc[1][3] += xv.y * wv.w;
        acc[2][0] += xv.z * wv.x; acc[2][1] += xv.z * wv.y; acc[2][2] += xv.z * wv.z; acc[2][3] += xv.z * wv.w;
        acc[3][0] += xv.w * wv.x; acc[3][1] += xv.w * wv.y; acc[3][2] += xv.w * wv.z; acc[3][3] += xv.w * wv.w;
    }

    float4 bv = *(const float4*)&bias[c0];
    #pragma unroll
    for (int i = 0; i < 4; i++) {
        int r = row0 + r0 + i;
        float4 o;
        o.x = fmaxf(acc[i][0] + bv.x, 0.0f);
        o.y = fmaxf(acc[i][1] + bv.y, 0.0f);
        o.z = fmaxf(acc[i][2] + bv.z, 0.0f);
        o.w = fmaxf(acc[i][3] + bv.w, 0.0f);
        *(float4*)&out[(size_t)r * 128 + c0] = o;
    }
}

extern "C" void kernel_launch(void* const* d_in, const int* in_sizes, int n_in,
                              void* d_out, int out_size, void* d_ws, size_t ws_size,
                              hipStream_t stream) {
    const int*   ann = (const int*)d_in[0];
    const int*   src = (const int*)d_in[1];
    const int*   dst = (const int*)d_in[2];
    const float* emb = (const float*)d_in[3];
    const float* Ws  = (const float*)d_in[4];
    const float* bs  = (const float*)d_in[5];
    float* out = (float*)d_out;

    const int N = in_sizes[0];   // 100000
    const int E = in_sizes[1];   // 1600000
    const int NB = (N + 255) / 256;   // 391

    // ws layout (ints/floats, all 16B-aligned regions):
    //   deg/cur [N] | row_ptr [N+1] | bsum [512] | eidx [E] | h_a [N*D]
    int* deg     = (int*)d_ws;
    int* row_ptr = deg + ((N + 3) & ~3);
    int* bsum    = row_ptr + ((N + 1 + 3) & ~3);
    int* eidx    = bsum + 512;
    float* h_a   = (float*)(eidx + ((E + 3) & ~3));

    // --- CSR build (once; reused by all 3 layers) ---
    hipMemsetAsync(deg, 0, (size_t)N * sizeof(int), stream);
    k_count<<<(E + 255) / 256, 256, 0, stream>>>(dst, deg, E);
    k_bsum<<<NB, 256, 0, stream>>>(deg, bsum, N);
    k_scanb<<<1, 512, 0, stream>>>(bsum, NB, row_ptr, N, E);
    k_scan_local<<<NB, 256, 0, stream>>>(deg, bsum, row_ptr, N);
    hipMemsetAsync(deg, 0, (size_t)N * sizeof(int), stream);   // reuse as cursor
    k_fill<<<(E + 255) / 256, 256, 0, stream>>>(src, dst, row_ptr, deg, eidx, E);

    // --- h0 = emb[annotation] into h_a ---
    k_gather<<<(N * 32 + 255) / 256, 256, 0, stream>>>(ann, (const float4*)emb, (float4*)h_a, N);

    // --- 3 layers: agg -> x (into hout buffer), gemm in place ---
    const float* hin = h_a;
    for (int l = 0; l < L; l++) {
        float* hout = (l & 1) ? h_a : out;   // l0: ->out, l1: ->h_a, l2: ->out
        k_agg<<<N / 4, 256, 0, stream>>>((const float2*)hin, row_ptr, eidx,
                                         (float2*)hout, N);
        k_gemm<<<N / 32, 256, 0, stream>>>(hout, Ws + (size_t)l * D * D,
                                           bs + (size_t)l * D, hout);
        hin = hout;
    }
}

// Round 3
// 848.993 us; speedup vs baseline: 9.9999x; 1.2015x over previous
//
#include <hip/hip_runtime.h>

// Graph_NN: 3-layer SAGE (gcn aggregator), N=100000, E=1600000, D=128, fp32.
// R3: (a) k_agg unrolled x8 -> 8 outstanding row loads per wave (was latency-
// serialized at 40% HBM BW, VALUBusy 13%); (b) persistent GEMM: 256 blocks,
// 512 threads, W staged in LDS once per block, grid-stride over 64-row tiles.

#define D 128
#define L 3

// ---------- CSR build ----------
__global__ void k_count(const int* __restrict__ dst, int* __restrict__ deg, int E) {
    int e = blockIdx.x * blockDim.x + threadIdx.x;
    if (e < E) atomicAdd(&deg[dst[e]], 1);
}

__global__ void k_bsum(const int* __restrict__ deg, int* __restrict__ bsum, int n) {
    __shared__ int s[256];
    int t = threadIdx.x, i = blockIdx.x * 256 + t;
    s[t] = (i < n) ? deg[i] : 0;
    __syncthreads();
    for (int off = 128; off > 0; off >>= 1) { if (t < off) s[t] += s[t + off]; __syncthreads(); }
    if (t == 0) bsum[blockIdx.x] = s[0];
}

// exclusive scan of bsum[0..nb) in one 512-thread block; also writes row_ptr[N]=E
__global__ void k_scanb(int* __restrict__ bsum, int nb, int* __restrict__ row_ptr, int N, int E) {
    __shared__ int s[512];
    int t = threadIdx.x;
    int v = (t < nb) ? bsum[t] : 0;
    s[t] = v;
    __syncthreads();
    for (int off = 1; off < 512; off <<= 1) {
        int x = (t >= off) ? s[t - off] : 0;
        __syncthreads();
        s[t] += x;
        __syncthreads();
    }
    if (t < nb) bsum[t] = s[t] - v;          // exclusive prefix
    if (t == 0) row_ptr[N] = E;
}

__global__ void k_scan_local(const int* __restrict__ deg, const int* __restrict__ bpre,
                             int* __restrict__ row_ptr, int n) {
    __shared__ int s[256];
    int t = threadIdx.x, i = blockIdx.x * 256 + t;
    int v = (i < n) ? deg[i] : 0;
    s[t] = v;
    __syncthreads();
    for (int off = 1; off < 256; off <<= 1) {
        int x = (t >= off) ? s[t - off] : 0;
        __syncthreads();
        s[t] += x;
        __syncthreads();
    }
    if (i < n) row_ptr[i] = bpre[blockIdx.x] + s[t] - v;   // exclusive
}

__global__ void k_fill(const int* __restrict__ src, const int* __restrict__ dst,
                       const int* __restrict__ row_ptr, int* __restrict__ cur,
                       int* __restrict__ eidx, int E) {
    int e = blockIdx.x * blockDim.x + threadIdx.x;
    if (e >= E) return;
    int d = dst[e];
    int pos = atomicAdd(&cur[d], 1);
    eidx[row_ptr[d] + pos] = src[e];
}

// ---------- h0 = emb[annotation] ----------
__global__ void k_gather(const int* __restrict__ ann, const float4* __restrict__ emb,
                         float4* __restrict__ h, int n) {
    int t = blockIdx.x * blockDim.x + threadIdx.x;
    if (t >= n * 32) return;
    int i = t >> 5, c = t & 31;
    h[i * 32 + c] = emb[ann[i] * 32 + c];
}

// ---------- aggregation: one 64-lane wave per node, 8 loads in flight ----------
// x[v] = (h[v] + sum_{u->v} h[u]) / (indeg(v)+1)
__global__ __launch_bounds__(256) void k_agg(
    const float2* __restrict__ h2, const int* __restrict__ row_ptr,
    const int* __restrict__ eidx, float2* __restrict__ x2, int n) {
    int v = blockIdx.x * 4 + (threadIdx.x >> 6);     // grid sized exactly (N%4==0)
    int lane = threadIdx.x & 63;
    int beg = row_ptr[v], end = row_ptr[v + 1];      // wave-uniform
    float2 acc = h2[(size_t)v * 64 + lane];
    int e = beg;
    for (; e + 8 <= end; e += 8) {
        int s0 = eidx[e+0], s1 = eidx[e+1], s2 = eidx[e+2], s3 = eidx[e+3];
        int s4 = eidx[e+4], s5 = eidx[e+5], s6 = eidx[e+6], s7 = eidx[e+7];
        float2 w0 = h2[(size_t)s0 * 64 + lane], w1 = h2[(size_t)s1 * 64 + lane];
        float2 w2 = h2[(size_t)s2 * 64 + lane], w3 = h2[(size_t)s3 * 64 + lane];
        float2 w4 = h2[(size_t)s4 * 64 + lane], w5 = h2[(size_t)s5 * 64 + lane];
        float2 w6 = h2[(size_t)s6 * 64 + lane], w7 = h2[(size_t)s7 * 64 + lane];
        acc.x += ((w0.x + w1.x) + (w2.x + w3.x)) + ((w4.x + w5.x) + (w6.x + w7.x));
        acc.y += ((w0.y + w1.y) + (w2.y + w3.y)) + ((w4.y + w5.y) + (w6.y + w7.y));
    }
    for (; e + 2 <= end; e += 2) {
        int s0 = eidx[e+0], s1 = eidx[e+1];
        float2 w0 = h2[(size_t)s0 * 64 + lane], w1 = h2[(size_t)s1 * 64 + lane];
        acc.x += w0.x + w1.x;
        acc.y += w0.y + w1.y;
    }
    for (; e < end; e++) {
        int s = eidx[e];
        float2 w = h2[(size_t)s * 64 + lane];
        acc.x += w.x; acc.y += w.y;
    }
    float sc = 1.0f / (float)(end - beg + 1);
    x2[(size_t)v * 64 + lane] = make_float2(acc.x * sc, acc.y * sc);
}

// ---------- out = relu(x @ W + b), persistent, in place ----------
// 256 blocks x 512 threads; W staged once; grid-stride over 64-row tiles.
// LDS: W 64KB + Xs 128*68*4=34.8KB = 98.8KB -> 1 block/CU, 8 waves/CU.
__global__ __launch_bounds__(512) void k_gemm(
    const float* __restrict__ x, const float* __restrict__ W,
    const float* __restrict__ bias, float* __restrict__ out, int n, int ntiles) {
    __shared__ float Wl[128 * 128];
    __shared__ float Xs[128 * 68];   // X^T tile: Xs[k*68 + r], r<64 (pad 4)
    int tid = threadIdx.x;

    // stage W: 4096 float4 over 512 threads = 8 each
    const float4* W4 = (const float4*)W;
    float4* Wl4 = (float4*)Wl;
    #pragma unroll
    for (int i = 0; i < 8; i++) Wl4[tid + i * 512] = W4[tid + i * 512];

    int r0 = (tid >> 5) * 4;         // 0,4,..,60
    int c0 = (tid & 31) * 4;         // 0,4,..,124
    float4 bv;                        // loaded after first sync barrier below

    for (int tile = blockIdx.x; tile < ntiles; tile += gridDim.x) {
        int row0 = tile * 64;
        __syncthreads();   // previous tile's Xs reads done (and W staged, 1st iter)
        {
            int r = tid >> 3;        // 0..63
            int qb = tid & 7;        // 0..7
            int grow = row0 + r;
            if (grow < n) {
                const float4* x4 = (const float4*)x;
                #pragma unroll
                for (int j = 0; j < 4; j++) {
                    int q = qb + j * 8;
                    float4 v = x4[(size_t)grow * 32 + q];
                    Xs[(q * 4 + 0) * 68 + r] = v.x;
                    Xs[(q * 4 + 1) * 68 + r] = v.y;
                    Xs[(q * 4 + 2) * 68 + r] = v.z;
                    Xs[(q * 4 + 3) * 68 + r] = v.w;
                }
            }
        }
        __syncthreads();

        float acc[4][4] = {};
        #pragma unroll 4
        for (int k = 0; k < 128; k++) {
            float4 xv = *(const float4*)&Xs[k * 68 + r0];
            float4 wv = *(const float4*)&Wl[k * 128 + c0];
            acc[0][0] += xv.x * wv.x; acc[0][1] += xv.x * wv.y; acc[0][2] += xv.x * wv.z; acc[0][3] += xv.x * wv.w;
            acc[1][0] += xv.y * wv.x; acc[1][1] += xv.y * wv.y; acc[1][2] += xv.y * wv.z; acc[1][3] += xv.y * wv.w;
            acc[2][0] += xv.z * wv.x; acc[2][1] += xv.z * wv.y; acc[2][2] += xv.z * wv.z; acc[2][3] += xv.z * wv.w;
            acc[3][0] += xv.w * wv.x; acc[3][1] += xv.w * wv.y; acc[3][2] += xv.w * wv.z; acc[3][3] += xv.w * wv.w;
        }

        bv = *(const float4*)&bias[c0];
        #pragma unroll
        for (int i = 0; i < 4; i++) {
            int r = row0 + r0 + i;
            if (r < n) {
                float4 o;
                o.x = fmaxf(acc[i][0] + bv.x, 0.0f);
                o.y = fmaxf(acc[i][1] + bv.y, 0.0f);
                o.z = fmaxf(acc[i][2] + bv.z, 0.0f);
                o.w = fmaxf(acc[i][3] + bv.w, 0.0f);
                *(float4*)&out[(size_t)r * 128 + c0] = o;
            }
        }
    }
}

extern "C" void kernel_launch(void* const* d_in, const int* in_sizes, int n_in,
                              void* d_out, int out_size, void* d_ws, size_t ws_size,
                              hipStream_t stream) {
    const int*   ann = (const int*)d_in[0];
    const int*   src = (const int*)d_in[1];
    const int*   dst = (const int*)d_in[2];
    const float* emb = (const float*)d_in[3];
    const float* Ws  = (const float*)d_in[4];
    const float* bs  = (const float*)d_in[5];
    float* out = (float*)d_out;

    const int N = in_sizes[0];   // 100000
    const int E = in_sizes[1];   // 1600000
    const int NB = (N + 255) / 256;        // 391
    const int NT = (N + 63) / 64;          // 1563 row tiles

    // ws layout: deg/cur [N] | row_ptr [N+1] | bsum [512] | eidx [E] | h_a [N*D]
    int* deg     = (int*)d_ws;
    int* row_ptr = deg + ((N + 3) & ~3);
    int* bsum    = row_ptr + ((N + 1 + 3) & ~3);
    int* eidx    = bsum + 512;
    float* h_a   = (float*)(eidx + ((E + 3) & ~3));

    // --- CSR build (once; reused by all 3 layers) ---
    hipMemsetAsync(deg, 0, (size_t)N * sizeof(int), stream);
    k_count<<<(E + 255) / 256, 256, 0, stream>>>(dst, deg, E);
    k_bsum<<<NB, 256, 0, stream>>>(deg, bsum, N);
    k_scanb<<<1, 512, 0, stream>>>(bsum, NB, row_ptr, N, E);
    k_scan_local<<<NB, 256, 0, stream>>>(deg, bsum, row_ptr, N);
    hipMemsetAsync(deg, 0, (size_t)N * sizeof(int), stream);   // reuse as cursor
    k_fill<<<(E + 255) / 256, 256, 0, stream>>>(src, dst, row_ptr, deg, eidx, E);

    // --- h0 = emb[annotation] into h_a ---
    k_gather<<<(N * 32 + 255) / 256, 256, 0, stream>>>(ann, (const float4*)emb, (float4*)h_a, N);

    // --- 3 layers: agg -> x (into hout buffer), gemm in place ---
    const float* hin = h_a;
    for (int l = 0; l < L; l++) {
        float* hout = (l & 1) ? h_a : out;   // l0: ->out, l1: ->h_a, l2: ->out
        k_agg<<<N / 4, 256, 0, stream>>>((const float2*)hin, row_ptr, eidx,
                                         (float2*)hout, N);
        k_gemm<<<256, 512, 0, stream>>>(hout, Ws + (size_t)l * D * D,
                                        bs + (size_t)l * D, hout, N, NT);
        hin = hout;
    }
}

// Round 4
// 848.717 us; speedup vs baseline: 10.0031x; 1.0003x over previous
//
#include <hip/hip_runtime.h>

// Graph_NN: 3-layer SAGE (gcn aggregator), N=100000, E=1600000, D=128, fp32.
// R4: (a) k_agg split-wave: lanes 0-31 even edge, 32-63 odd edge, float4/lane
//     -> 2 rows (1KB) per instruction, 16 rows in flight with unroll 8.
// (b) GEMM: 128-row tiles, 8x4 micro-tile (3 ds_read_b128 per 32 FMA).

#define D 128
#define L 3

// ---------- CSR build ----------
__global__ void k_count(const int* __restrict__ dst, int* __restrict__ deg, int E) {
    int e = blockIdx.x * blockDim.x + threadIdx.x;
    if (e < E) atomicAdd(&deg[dst[e]], 1);
}

__global__ void k_bsum(const int* __restrict__ deg, int* __restrict__ bsum, int n) {
    __shared__ int s[256];
    int t = threadIdx.x, i = blockIdx.x * 256 + t;
    s[t] = (i < n) ? deg[i] : 0;
    __syncthreads();
    for (int off = 128; off > 0; off >>= 1) { if (t < off) s[t] += s[t + off]; __syncthreads(); }
    if (t == 0) bsum[blockIdx.x] = s[0];
}

// exclusive scan of bsum[0..nb) in one 512-thread block; also writes row_ptr[N]=E
__global__ void k_scanb(int* __restrict__ bsum, int nb, int* __restrict__ row_ptr, int N, int E) {
    __shared__ int s[512];
    int t = threadIdx.x;
    int v = (t < nb) ? bsum[t] : 0;
    s[t] = v;
    __syncthreads();
    for (int off = 1; off < 512; off <<= 1) {
        int x = (t >= off) ? s[t - off] : 0;
        __syncthreads();
        s[t] += x;
        __syncthreads();
    }
    if (t < nb) bsum[t] = s[t] - v;          // exclusive prefix
    if (t == 0) row_ptr[N] = E;
}

__global__ void k_scan_local(const int* __restrict__ deg, const int* __restrict__ bpre,
                             int* __restrict__ row_ptr, int n) {
    __shared__ int s[256];
    int t = threadIdx.x, i = blockIdx.x * 256 + t;
    int v = (i < n) ? deg[i] : 0;
    s[t] = v;
    __syncthreads();
    for (int off = 1; off < 256; off <<= 1) {
        int x = (t >= off) ? s[t - off] : 0;
        __syncthreads();
        s[t] += x;
        __syncthreads();
    }
    if (i < n) row_ptr[i] = bpre[blockIdx.x] + s[t] - v;   // exclusive
}

__global__ void k_fill(const int* __restrict__ src, const int* __restrict__ dst,
                       const int* __restrict__ row_ptr, int* __restrict__ cur,
                       int* __restrict__ eidx, int E) {
    int e = blockIdx.x * blockDim.x + threadIdx.x;
    if (e >= E) return;
    int d = dst[e];
    int pos = atomicAdd(&cur[d], 1);
    eidx[row_ptr[d] + pos] = src[e];
}

// ---------- h0 = emb[annotation] ----------
__global__ void k_gather(const int* __restrict__ ann, const float4* __restrict__ emb,
                         float4* __restrict__ h, int n) {
    int t = blockIdx.x * blockDim.x + threadIdx.x;
    if (t >= n * 32) return;
    int i = t >> 5, c = t & 31;
    h[i * 32 + c] = emb[ann[i] * 32 + c];
}

// ---------- aggregation: one wave per node, split-wave 2 edges/instr ----------
// x[v] = (h[v] + sum_{u->v} h[u]) / (indeg(v)+1)
// lanes 0-31 (half=0): even edge of pair + self term; lanes 32-63: odd edge.
__global__ __launch_bounds__(256) void k_agg(
    const float4* __restrict__ h4, const int* __restrict__ row_ptr,
    const int* __restrict__ eidx, float4* __restrict__ x4, int n) {
    int v = blockIdx.x * 4 + (threadIdx.x >> 6);     // grid sized exactly (N%4==0)
    int lane = threadIdx.x & 63;
    int half = lane >> 5;        // 0 or 1
    int q = lane & 31;           // float4 index within 128-float row
    int beg = row_ptr[v], end = row_ptr[v + 1];
    int deg = end - beg;
    float4 acc = make_float4(0.f, 0.f, 0.f, 0.f);
    if (half == 0) acc = h4[(size_t)v * 32 + q];     // self term once

    int pairs = deg >> 1;
    int p = 0;
    for (; p + 8 <= pairs; p += 8) {
        int eb = beg + 2 * p + half;
        int s0 = eidx[eb +  0], s1 = eidx[eb +  2], s2 = eidx[eb +  4], s3 = eidx[eb +  6];
        int s4 = eidx[eb +  8], s5 = eidx[eb + 10], s6 = eidx[eb + 12], s7 = eidx[eb + 14];
        float4 w0 = h4[(size_t)s0 * 32 + q], w1 = h4[(size_t)s1 * 32 + q];
        float4 w2 = h4[(size_t)s2 * 32 + q], w3 = h4[(size_t)s3 * 32 + q];
        float4 w4 = h4[(size_t)s4 * 32 + q], w5 = h4[(size_t)s5 * 32 + q];
        float4 w6 = h4[(size_t)s6 * 32 + q], w7 = h4[(size_t)s7 * 32 + q];
        acc.x += ((w0.x + w1.x) + (w2.x + w3.x)) + ((w4.x + w5.x) + (w6.x + w7.x));
        acc.y += ((w0.y + w1.y) + (w2.y + w3.y)) + ((w4.y + w5.y) + (w6.y + w7.y));
        acc.z += ((w0.z + w1.z) + (w2.z + w3.z)) + ((w4.z + w5.z) + (w6.z + w7.z));
        acc.w += ((w0.w + w1.w) + (w2.w + w3.w)) + ((w4.w + w5.w) + (w6.w + w7.w));
    }
    for (; p < pairs; p++) {
        int s = eidx[beg + 2 * p + half];
        float4 w = h4[(size_t)s * 32 + q];
        acc.x += w.x; acc.y += w.y; acc.z += w.z; acc.w += w.w;
    }
    if ((deg & 1) && half == 0) {                    // odd tail edge
        int s = eidx[end - 1];
        float4 w = h4[(size_t)s * 32 + q];
        acc.x += w.x; acc.y += w.y; acc.z += w.z; acc.w += w.w;
    }
    // combine halves: lanes 0-31 += lanes 32-63
    acc.x += __shfl_down(acc.x, 32, 64);
    acc.y += __shfl_down(acc.y, 32, 64);
    acc.z += __shfl_down(acc.z, 32, 64);
    acc.w += __shfl_down(acc.w, 32, 64);
    if (half == 0) {
        float sc = 1.0f / (float)(deg + 1);
        x4[(size_t)v * 32 + q] = make_float4(acc.x * sc, acc.y * sc, acc.z * sc, acc.w * sc);
    }
}

// ---------- out = relu(x @ W + b), persistent, in place ----------
// 256 blocks x 512 threads; W staged once; 128-row tiles; 8x4 micro-tile.
// LDS: W 64KB + Xs 128*132*4 = 67.6KB = 131.6KB -> 1 block/CU, 8 waves/CU.
__global__ __launch_bounds__(512) void k_gemm(
    const float* __restrict__ x, const float* __restrict__ W,
    const float* __restrict__ bias, float* __restrict__ out, int n, int ntiles) {
    __shared__ float Wl[128 * 128];
    __shared__ float Xs[128 * 132];  // X^T tile: Xs[k*132 + r], r<128 (pad 4)
    int tid = threadIdx.x;

    // stage W: 4096 float4 over 512 threads = 8 each
    const float4* W4 = (const float4*)W;
    float4* Wl4 = (float4*)Wl;
    #pragma unroll
    for (int i = 0; i < 8; i++) Wl4[tid + i * 512] = W4[tid + i * 512];

    int c0 = (tid & 31) * 4;         // 0,4,..,124
    int r0 = (tid >> 5) * 8;         // 0,8,..,120
    float4 bv = *(const float4*)&bias[c0];

    for (int tile = blockIdx.x; tile < ntiles; tile += gridDim.x) {
        int row0 = tile * 128;
        __syncthreads();   // previous tile's Xs reads done (and W staged, 1st iter)
        {
            int r = tid >> 2;        // 0..127
            int qb = tid & 3;        // 0..3
            int grow = row0 + r;
            if (grow < n) {
                const float4* x4p = (const float4*)x;
                #pragma unroll
                for (int j = 0; j < 8; j++) {
                    int q = qb + j * 4;
                    float4 v = x4p[(size_t)grow * 32 + q];
                    Xs[(q * 4 + 0) * 132 + r] = v.x;
                    Xs[(q * 4 + 1) * 132 + r] = v.y;
                    Xs[(q * 4 + 2) * 132 + r] = v.z;
                    Xs[(q * 4 + 3) * 132 + r] = v.w;
                }
            }
        }
        __syncthreads();

        float acc[8][4] = {};
        #pragma unroll 4
        for (int k = 0; k < 128; k++) {
            float4 xa = *(const float4*)&Xs[k * 132 + r0];
            float4 xb = *(const float4*)&Xs[k * 132 + r0 + 4];
            float4 wv = *(const float4*)&Wl[k * 128 + c0];
            acc[0][0] += xa.x * wv.x; acc[0][1] += xa.x * wv.y; acc[0][2] += xa.x * wv.z; acc[0][3] += xa.x * wv.w;
            acc[1][0] += xa.y * wv.x; acc[1][1] += xa.y * wv.y; acc[1][2] += xa.y * wv.z; acc[1][3] += xa.y * wv.w;
            acc[2][0] += xa.z * wv.x; acc[2][1] += xa.z * wv.y; acc[2][2] += xa.z * wv.z; acc[2][3] += xa.z * wv.w;
            acc[3][0] += xa.w * wv.x; acc[3][1] += xa.w * wv.y; acc[3][2] += xa.w * wv.z; acc[3][3] += xa.w * wv.w;
            acc[4][0] += xb.x * wv.x; acc[4][1] += xb.x * wv.y; acc[4][2] += xb.x * wv.z; acc[4][3] += xb.x * wv.w;
            acc[5][0] += xb.y * wv.x; acc[5][1] += xb.y * wv.y; acc[5][2] += xb.y * wv.z; acc[5][3] += xb.y * wv.w;
            acc[6][0] += xb.z * wv.x; acc[6][1] += xb.z * wv.y; acc[6][2] += xb.z * wv.z; acc[6][3] += xb.z * wv.w;
            acc[7][0] += xb.w * wv.x; acc[7][1] += xb.w * wv.y; acc[7][2] += xb.w * wv.z; acc[7][3] += xb.w * wv.w;
        }

        #pragma unroll
        for (int i = 0; i < 8; i++) {
            int r = row0 + r0 + i;
            if (r < n) {
                float4 o;
                o.x = fmaxf(acc[i][0] + bv.x, 0.0f);
                o.y = fmaxf(acc[i][1] + bv.y, 0.0f);
                o.z = fmaxf(acc[i][2] + bv.z, 0.0f);
                o.w = fmaxf(acc[i][3] + bv.w, 0.0f);
                *(float4*)&out[(size_t)r * 128 + c0] = o;
            }
        }
    }
}

extern "C" void kernel_launch(void* const* d_in, const int* in_sizes, int n_in,
                              void* d_out, int out_size, void* d_ws, size_t ws_size,
                              hipStream_t stream) {
    const int*   ann = (const int*)d_in[0];
    const int*   src = (const int*)d_in[1];
    const int*   dst = (const int*)d_in[2];
    const float* emb = (const float*)d_in[3];
    const float* Ws  = (const float*)d_in[4];
    const float* bs  = (const float*)d_in[5];
    float* out = (float*)d_out;

    const int N = in_sizes[0];   // 100000
    const int E = in_sizes[1];   // 1600000
    const int NB = (N + 255) / 256;        // 391
    const int NT = (N + 127) / 128;        // 782 row tiles

    // ws layout: deg/cur [N] | row_ptr [N+1] | bsum [512] | eidx [E] | h_a [N*D]
    int* deg     = (int*)d_ws;
    int* row_ptr = deg + ((N + 3) & ~3);
    int* bsum    = row_ptr + ((N + 1 + 3) & ~3);
    int* eidx    = bsum + 512;
    float* h_a   = (float*)(eidx + ((E + 3) & ~3));

    // --- CSR build (once; reused by all 3 layers) ---
    hipMemsetAsync(deg, 0, (size_t)N * sizeof(int), stream);
    k_count<<<(E + 255) / 256, 256, 0, stream>>>(dst, deg, E);
    k_bsum<<<NB, 256, 0, stream>>>(deg, bsum, N);
    k_scanb<<<1, 512, 0, stream>>>(bsum, NB, row_ptr, N, E);
    k_scan_local<<<NB, 256, 0, stream>>>(deg, bsum, row_ptr, N);
    hipMemsetAsync(deg, 0, (size_t)N * sizeof(int), stream);   // reuse as cursor
    k_fill<<<(E + 255) / 256, 256, 0, stream>>>(src, dst, row_ptr, deg, eidx, E);

    // --- h0 = emb[annotation] into h_a ---
    k_gather<<<(N * 32 + 255) / 256, 256, 0, stream>>>(ann, (const float4*)emb, (float4*)h_a, N);

    // --- 3 layers: agg -> x (into hout buffer), gemm in place ---
    const float* hin = h_a;
    for (int l = 0; l < L; l++) {
        float* hout = (l & 1) ? h_a : out;   // l0: ->out, l1: ->h_a, l2: ->out
        k_agg<<<N / 4, 256, 0, stream>>>((const float4*)hin, row_ptr, eidx,
                                         (float4*)hout, N);
        k_gemm<<<256, 512, 0, stream>>>(hout, Ws + (size_t)l * D * D,
                                        bs + (size_t)l * D, hout, N, NT);
        hin = hout;
    }
}

// Round 5
// 775.195 us; speedup vs baseline: 10.9518x; 1.0948x over previous
//
#include <hip/hip_runtime.h>

// Graph_NN: 3-layer SAGE (gcn aggregator), N=100000, E=1600000, D=128, fp32.
// R5: (a) layer-1 agg gathers directly from emb (V=5000 rows = 2.56MB, fits
//     per-XCD L2) via aidx[e]=ann[src[e]] precomputed in k_fill; h0 never
//     materialized. Layers 2-3 agg unchanged (genuinely N-row working set,
//     pinned at ~3.9 TB/s beyond-L2 ceiling).
// (b) GEMM: 256 thr, 8x8 micro-tile (64 FMA per 4 ds_read_b128 per k),
//     register prefetch of next row-tile overlaps global staging w/ compute.

#define D 128
#define L 3

// ---------- CSR build ----------
__global__ void k_count(const int* __restrict__ dst, int* __restrict__ deg, int E) {
    int e = blockIdx.x * blockDim.x + threadIdx.x;
    if (e < E) atomicAdd(&deg[dst[e]], 1);
}

__global__ void k_bsum(const int* __restrict__ deg, int* __restrict__ bsum, int n) {
    __shared__ int s[256];
    int t = threadIdx.x, i = blockIdx.x * 256 + t;
    s[t] = (i < n) ? deg[i] : 0;
    __syncthreads();
    for (int off = 128; off > 0; off >>= 1) { if (t < off) s[t] += s[t + off]; __syncthreads(); }
    if (t == 0) bsum[blockIdx.x] = s[0];
}

// exclusive scan of bsum[0..nb) in one 512-thread block; also writes row_ptr[N]=E
__global__ void k_scanb(int* __restrict__ bsum, int nb, int* __restrict__ row_ptr, int N, int E) {
    __shared__ int s[512];
    int t = threadIdx.x;
    int v = (t < nb) ? bsum[t] : 0;
    s[t] = v;
    __syncthreads();
    for (int off = 1; off < 512; off <<= 1) {
        int x = (t >= off) ? s[t - off] : 0;
        __syncthreads();
        s[t] += x;
        __syncthreads();
    }
    if (t < nb) bsum[t] = s[t] - v;          // exclusive prefix
    if (t == 0) row_ptr[N] = E;
}

__global__ void k_scan_local(const int* __restrict__ deg, const int* __restrict__ bpre,
                             int* __restrict__ row_ptr, int n) {
    __shared__ int s[256];
    int t = threadIdx.x, i = blockIdx.x * 256 + t;
    int v = (i < n) ? deg[i] : 0;
    s[t] = v;
    __syncthreads();
    for (int off = 1; off < 256; off <<= 1) {
        int x = (t >= off) ? s[t - off] : 0;
        __syncthreads();
        s[t] += x;
        __syncthreads();
    }
    if (i < n) row_ptr[i] = bpre[blockIdx.x] + s[t] - v;   // exclusive
}

// fill eidx (src node) and aidx (annotation of src node) grouped by dst
__global__ void k_fill(const int* __restrict__ src, const int* __restrict__ dst,
                       const int* __restrict__ ann, const int* __restrict__ row_ptr,
                       int* __restrict__ cur, int* __restrict__ eidx,
                       int* __restrict__ aidx, int E) {
    int e = blockIdx.x * blockDim.x + threadIdx.x;
    if (e >= E) return;
    int d = dst[e];
    int s = src[e];
    int pos = atomicAdd(&cur[d], 1);
    int base = row_ptr[d] + pos;
    eidx[base] = s;
    aidx[base] = ann[s];
}

// ---------- layer-1 aggregation straight from emb (L2-resident, 2.56MB) ----
// x[v] = (emb[ann[v]] + sum_{u->v} emb[ann[u]]) / (indeg(v)+1)
__global__ __launch_bounds__(256) void k_agg_emb(
    const float4* __restrict__ emb4, const int* __restrict__ ann,
    const int* __restrict__ row_ptr, const int* __restrict__ aidx,
    float4* __restrict__ x4, int n) {
    int v = blockIdx.x * 4 + (threadIdx.x >> 6);
    int lane = threadIdx.x & 63;
    int half = lane >> 5;
    int q = lane & 31;
    int beg = row_ptr[v], end = row_ptr[v + 1];
    int deg = end - beg;
    float4 acc = make_float4(0.f, 0.f, 0.f, 0.f);
    if (half == 0) acc = emb4[(size_t)ann[v] * 32 + q];   // self term once

    int pairs = deg >> 1;
    int p = 0;
    for (; p + 8 <= pairs; p += 8) {
        int eb = beg + 2 * p + half;
        int s0 = aidx[eb +  0], s1 = aidx[eb +  2], s2 = aidx[eb +  4], s3 = aidx[eb +  6];
        int s4 = aidx[eb +  8], s5 = aidx[eb + 10], s6 = aidx[eb + 12], s7 = aidx[eb + 14];
        float4 w0 = emb4[(size_t)s0 * 32 + q], w1 = emb4[(size_t)s1 * 32 + q];
        float4 w2 = emb4[(size_t)s2 * 32 + q], w3 = emb4[(size_t)s3 * 32 + q];
        float4 w4 = emb4[(size_t)s4 * 32 + q], w5 = emb4[(size_t)s5 * 32 + q];
        float4 w6 = emb4[(size_t)s6 * 32 + q], w7 = emb4[(size_t)s7 * 32 + q];
        acc.x += ((w0.x + w1.x) + (w2.x + w3.x)) + ((w4.x + w5.x) + (w6.x + w7.x));
        acc.y += ((w0.y + w1.y) + (w2.y + w3.y)) + ((w4.y + w5.y) + (w6.y + w7.y));
        acc.z += ((w0.z + w1.z) + (w2.z + w3.z)) + ((w4.z + w5.z) + (w6.z + w7.z));
        acc.w += ((w0.w + w1.w) + (w2.w + w3.w)) + ((w4.w + w5.w) + (w6.w + w7.w));
    }
    for (; p < pairs; p++) {
        int s = aidx[beg + 2 * p + half];
        float4 w = emb4[(size_t)s * 32 + q];
        acc.x += w.x; acc.y += w.y; acc.z += w.z; acc.w += w.w;
    }
    if ((deg & 1) && half == 0) {
        int s = aidx[end - 1];
        float4 w = emb4[(size_t)s * 32 + q];
        acc.x += w.x; acc.y += w.y; acc.z += w.z; acc.w += w.w;
    }
    acc.x += __shfl_down(acc.x, 32, 64);
    acc.y += __shfl_down(acc.y, 32, 64);
    acc.z += __shfl_down(acc.z, 32, 64);
    acc.w += __shfl_down(acc.w, 32, 64);
    if (half == 0) {
        float sc = 1.0f / (float)(deg + 1);
        x4[(size_t)v * 32 + q] = make_float4(acc.x * sc, acc.y * sc, acc.z * sc, acc.w * sc);
    }
}

// ---------- layers 2-3 aggregation from h (unchanged split-wave) ----------
__global__ __launch_bounds__(256) void k_agg(
    const float4* __restrict__ h4, const int* __restrict__ row_ptr,
    const int* __restrict__ eidx, float4* __restrict__ x4, int n) {
    int v = blockIdx.x * 4 + (threadIdx.x >> 6);
    int lane = threadIdx.x & 63;
    int half = lane >> 5;
    int q = lane & 31;
    int beg = row_ptr[v], end = row_ptr[v + 1];
    int deg = end - beg;
    float4 acc = make_float4(0.f, 0.f, 0.f, 0.f);
    if (half == 0) acc = h4[(size_t)v * 32 + q];

    int pairs = deg >> 1;
    int p = 0;
    for (; p + 8 <= pairs; p += 8) {
        int eb = beg + 2 * p + half;
        int s0 = eidx[eb +  0], s1 = eidx[eb +  2], s2 = eidx[eb +  4], s3 = eidx[eb +  6];
        int s4 = eidx[eb +  8], s5 = eidx[eb + 10], s6 = eidx[eb + 12], s7 = eidx[eb + 14];
        float4 w0 = h4[(size_t)s0 * 32 + q], w1 = h4[(size_t)s1 * 32 + q];
        float4 w2 = h4[(size_t)s2 * 32 + q], w3 = h4[(size_t)s3 * 32 + q];
        float4 w4 = h4[(size_t)s4 * 32 + q], w5 = h4[(size_t)s5 * 32 + q];
        float4 w6 = h4[(size_t)s6 * 32 + q], w7 = h4[(size_t)s7 * 32 + q];
        acc.x += ((w0.x + w1.x) + (w2.x + w3.x)) + ((w4.x + w5.x) + (w6.x + w7.x));
        acc.y += ((w0.y + w1.y) + (w2.y + w3.y)) + ((w4.y + w5.y) + (w6.y + w7.y));
        acc.z += ((w0.z + w1.z) + (w2.z + w3.z)) + ((w4.z + w5.z) + (w6.z + w7.z));
        acc.w += ((w0.w + w1.w) + (w2.w + w3.w)) + ((w4.w + w5.w) + (w6.w + w7.w));
    }
    for (; p < pairs; p++) {
        int s = eidx[beg + 2 * p + half];
        float4 w = h4[(size_t)s * 32 + q];
        acc.x += w.x; acc.y += w.y; acc.z += w.z; acc.w += w.w;
    }
    if ((deg & 1) && half == 0) {
        int s = eidx[end - 1];
        float4 w = h4[(size_t)s * 32 + q];
        acc.x += w.x; acc.y += w.y; acc.z += w.z; acc.w += w.w;
    }
    acc.x += __shfl_down(acc.x, 32, 64);
    acc.y += __shfl_down(acc.y, 32, 64);
    acc.z += __shfl_down(acc.z, 32, 64);
    acc.w += __shfl_down(acc.w, 32, 64);
    if (half == 0) {
        float sc = 1.0f / (float)(deg + 1);
        x4[(size_t)v * 32 + q] = make_float4(acc.x * sc, acc.y * sc, acc.z * sc, acc.w * sc);
    }
}

// ---------- out = relu(x @ W + b), persistent, in place, reg-prefetch ------
// 256 blocks x 256 threads; W staged once; 128-row tiles; 8x8 micro-tile.
// LDS: W 64KB + Xs 128*132*4 = 67.6KB = 131.6KB -> 1 block/CU.
__global__ __launch_bounds__(256) void k_gemm(
    const float* __restrict__ x, const float* __restrict__ W,
    const float* __restrict__ bias, float* __restrict__ out, int n, int ntiles) {
    __shared__ float Wl[128 * 128];
    __shared__ float Xs[128 * 132];  // X^T: Xs[k*132 + r]
    int tid = threadIdx.x;

    const float4* W4 = (const float4*)W;
    float4* Wl4 = (float4*)Wl;
    #pragma unroll
    for (int i = 0; i < 16; i++) Wl4[tid + i * 256] = W4[tid + i * 256];

    int c0 = (tid & 15) * 8;         // 0,8,..,120
    int r0 = (tid >> 4) * 8;         // 0,8,..,120
    int sr = tid >> 1;               // staging row 0..127
    int sq = (tid & 1) * 16;         // staging float4 base 0 or 16
    const float4* x4p = (const float4*)x;

    float4 pf[16];
    int tile = blockIdx.x;
    if (tile < ntiles) {
        int grow = tile * 128 + sr;
        if (grow < n) {
            #pragma unroll
            for (int j = 0; j < 16; j++) pf[j] = x4p[(size_t)grow * 32 + sq + j];
        }
    }
    float4 bv0 = *(const float4*)&bias[c0];
    float4 bv1 = *(const float4*)&bias[c0 + 4];

    for (; tile < ntiles; tile += gridDim.x) {
        __syncthreads();             // prior tile's Xs reads done (& Wl staged)
        {
            int grow = tile * 128 + sr;
            if (grow < n) {
                #pragma unroll
                for (int j = 0; j < 16; j++) {
                    int q = sq + j;
                    Xs[(q * 4 + 0) * 132 + sr] = pf[j].x;
                    Xs[(q * 4 + 1) * 132 + sr] = pf[j].y;
                    Xs[(q * 4 + 2) * 132 + sr] = pf[j].z;
                    Xs[(q * 4 + 3) * 132 + sr] = pf[j].w;
                }
            }
        }
        __syncthreads();

        // prefetch next tile while computing this one
        int ntile = tile + gridDim.x;
        if (ntile < ntiles) {
            int grow = ntile * 128 + sr;
            if (grow < n) {
                #pragma unroll
                for (int j = 0; j < 16; j++) pf[j] = x4p[(size_t)grow * 32 + sq + j];
            }
        }

        float acc[8][8] = {};
        #pragma unroll 2
        for (int k = 0; k < 128; k++) {
            float4 xa = *(const float4*)&Xs[k * 132 + r0];
            float4 xb = *(const float4*)&Xs[k * 132 + r0 + 4];
            float4 wa = *(const float4*)&Wl[k * 128 + c0];
            float4 wb = *(const float4*)&Wl[k * 128 + c0 + 4];
            float xr[8] = {xa.x, xa.y, xa.z, xa.w, xb.x, xb.y, xb.z, xb.w};
            float wc[8] = {wa.x, wa.y, wa.z, wa.w, wb.x, wb.y, wb.z, wb.w};
            #pragma unroll
            for (int i = 0; i < 8; i++)
                #pragma unroll
                for (int j = 0; j < 8; j++)
                    acc[i][j] += xr[i] * wc[j];
        }

        int row0 = tile * 128;
        #pragma unroll
        for (int i = 0; i < 8; i++) {
            int r = row0 + r0 + i;
            if (r < n) {
                float4 o0, o1;
                o0.x = fmaxf(acc[i][0] + bv0.x, 0.f);
                o0.y = fmaxf(acc[i][1] + bv0.y, 0.f);
                o0.z = fmaxf(acc[i][2] + bv0.z, 0.f);
                o0.w = fmaxf(acc[i][3] + bv0.w, 0.f);
                o1.x = fmaxf(acc[i][4] + bv1.x, 0.f);
                o1.y = fmaxf(acc[i][5] + bv1.y, 0.f);
                o1.z = fmaxf(acc[i][6] + bv1.z, 0.f);
                o1.w = fmaxf(acc[i][7] + bv1.w, 0.f);
                *(float4*)&out[(size_t)r * 128 + c0] = o0;
                *(float4*)&out[(size_t)r * 128 + c0 + 4] = o1;
            }
        }
    }
}

extern "C" void kernel_launch(void* const* d_in, const int* in_sizes, int n_in,
                              void* d_out, int out_size, void* d_ws, size_t ws_size,
                              hipStream_t stream) {
    const int*   ann = (const int*)d_in[0];
    const int*   src = (const int*)d_in[1];
    const int*   dst = (const int*)d_in[2];
    const float* emb = (const float*)d_in[3];
    const float* Ws  = (const float*)d_in[4];
    const float* bs  = (const float*)d_in[5];
    float* out = (float*)d_out;

    const int N = in_sizes[0];   // 100000
    const int E = in_sizes[1];   // 1600000
    const int NB = (N + 255) / 256;        // 391
    const int NT = (N + 127) / 128;        // 782 row tiles

    // ws: deg/cur [N] | row_ptr [N+1] | bsum [512] | eidx [E] | aidx [E] | h_a [N*D]
    int* deg     = (int*)d_ws;
    int* row_ptr = deg + ((N + 3) & ~3);
    int* bsum    = row_ptr + ((N + 1 + 3) & ~3);
    int* eidx    = bsum + 512;
    int* aidx    = eidx + ((E + 3) & ~3);
    float* h_a   = (float*)(aidx + ((E + 3) & ~3));

    // --- CSR build (once; reused by all 3 layers) ---
    hipMemsetAsync(deg, 0, (size_t)N * sizeof(int), stream);
    k_count<<<(E + 255) / 256, 256, 0, stream>>>(dst, deg, E);
    k_bsum<<<NB, 256, 0, stream>>>(deg, bsum, N);
    k_scanb<<<1, 512, 0, stream>>>(bsum, NB, row_ptr, N, E);
    k_scan_local<<<NB, 256, 0, stream>>>(deg, bsum, row_ptr, N);
    hipMemsetAsync(deg, 0, (size_t)N * sizeof(int), stream);   // reuse as cursor
    k_fill<<<(E + 255) / 256, 256, 0, stream>>>(src, dst, ann, row_ptr, deg, eidx, aidx, E);

    // --- layer 1: agg straight from emb -> out; gemm in place ---
    k_agg_emb<<<N / 4, 256, 0, stream>>>((const float4*)emb, ann, row_ptr, aidx,
                                         (float4*)out, N);
    k_gemm<<<256, 256, 0, stream>>>(out, Ws, bs, out, N, NT);

    // --- layer 2: out -> h_a ---
    k_agg<<<N / 4, 256, 0, stream>>>((const float4*)out, row_ptr, eidx,
                                     (float4*)h_a, N);
    k_gemm<<<256, 256, 0, stream>>>(h_a, Ws + (size_t)D * D, bs + D, h_a, N, NT);

    // --- layer 3: h_a -> out ---
    k_agg<<<N / 4, 256, 0, stream>>>((const float4*)h_a, row_ptr, eidx,
                                     (float4*)out, N);
    k_gemm<<<256, 256, 0, stream>>>(out, Ws + (size_t)2 * D * D, bs + 2 * D, out, N, NT);
}

// Round 6
// 707.665 us; speedup vs baseline: 11.9969x; 1.0954x over previous
//
#include <hip/hip_runtime.h>
#include <hip/hip_fp16.h>

// Graph_NN: 3-layer SAGE (gcn aggregator), N=100000, E=1600000, D=128, fp32.
// R6: intermediate h (h1,h2) stored fp16 -> layers 2-3 aggregation reads half
// the bytes (256B/row). R3/R4 showed agg is pinned at ~3.9 TB/s on the random
// row L2-miss path regardless of MLP, so bytes are the only lever. fp32
// accumulation; quantization adds ~1-2e-5/layer vs 1.27e-4 budget.
// Quad-split wave: 4 groups x 16 lanes x 16B = 4 rows per instruction.

#define D 128
#define L 3

// ---------- CSR build ----------
__global__ void k_count(const int* __restrict__ dst, int* __restrict__ deg, int E) {
    int e = blockIdx.x * blockDim.x + threadIdx.x;
    if (e < E) atomicAdd(&deg[dst[e]], 1);
}

__global__ void k_bsum(const int* __restrict__ deg, int* __restrict__ bsum, int n) {
    __shared__ int s[256];
    int t = threadIdx.x, i = blockIdx.x * 256 + t;
    s[t] = (i < n) ? deg[i] : 0;
    __syncthreads();
    for (int off = 128; off > 0; off >>= 1) { if (t < off) s[t] += s[t + off]; __syncthreads(); }
    if (t == 0) bsum[blockIdx.x] = s[0];
}

__global__ void k_scanb(int* __restrict__ bsum, int nb, int* __restrict__ row_ptr, int N, int E) {
    __shared__ int s[512];
    int t = threadIdx.x;
    int v = (t < nb) ? bsum[t] : 0;
    s[t] = v;
    __syncthreads();
    for (int off = 1; off < 512; off <<= 1) {
        int x = (t >= off) ? s[t - off] : 0;
        __syncthreads();
        s[t] += x;
        __syncthreads();
    }
    if (t < nb) bsum[t] = s[t] - v;          // exclusive prefix
    if (t == 0) row_ptr[N] = E;
}

__global__ void k_scan_local(const int* __restrict__ deg, const int* __restrict__ bpre,
                             int* __restrict__ row_ptr, int n) {
    __shared__ int s[256];
    int t = threadIdx.x, i = blockIdx.x * 256 + t;
    int v = (i < n) ? deg[i] : 0;
    s[t] = v;
    __syncthreads();
    for (int off = 1; off < 256; off <<= 1) {
        int x = (t >= off) ? s[t - off] : 0;
        __syncthreads();
        s[t] += x;
        __syncthreads();
    }
    if (i < n) row_ptr[i] = bpre[blockIdx.x] + s[t] - v;   // exclusive
}

__global__ void k_fill(const int* __restrict__ src, const int* __restrict__ dst,
                       const int* __restrict__ ann, const int* __restrict__ row_ptr,
                       int* __restrict__ cur, int* __restrict__ eidx,
                       int* __restrict__ aidx, int E) {
    int e = blockIdx.x * blockDim.x + threadIdx.x;
    if (e >= E) return;
    int d = dst[e];
    int s = src[e];
    int pos = atomicAdd(&cur[d], 1);
    int base = row_ptr[d] + pos;
    eidx[base] = s;
    aidx[base] = ann[s];
}

// ---------- layer-1 aggregation straight from emb (L2-resident, fp32) ------
__global__ __launch_bounds__(256) void k_agg_emb(
    const float4* __restrict__ emb4, const int* __restrict__ ann,
    const int* __restrict__ row_ptr, const int* __restrict__ aidx,
    float4* __restrict__ x4, int n) {
    int v = blockIdx.x * 4 + (threadIdx.x >> 6);
    int lane = threadIdx.x & 63;
    int half = lane >> 5;
    int q = lane & 31;
    int beg = row_ptr[v], end = row_ptr[v + 1];
    int deg = end - beg;
    float4 acc = make_float4(0.f, 0.f, 0.f, 0.f);
    if (half == 0) acc = emb4[(size_t)ann[v] * 32 + q];   // self term once

    int pairs = deg >> 1;
    int p = 0;
    for (; p + 8 <= pairs; p += 8) {
        int eb = beg + 2 * p + half;
        int s0 = aidx[eb +  0], s1 = aidx[eb +  2], s2 = aidx[eb +  4], s3 = aidx[eb +  6];
        int s4 = aidx[eb +  8], s5 = aidx[eb + 10], s6 = aidx[eb + 12], s7 = aidx[eb + 14];
        float4 w0 = emb4[(size_t)s0 * 32 + q], w1 = emb4[(size_t)s1 * 32 + q];
        float4 w2 = emb4[(size_t)s2 * 32 + q], w3 = emb4[(size_t)s3 * 32 + q];
        float4 w4 = emb4[(size_t)s4 * 32 + q], w5 = emb4[(size_t)s5 * 32 + q];
        float4 w6 = emb4[(size_t)s6 * 32 + q], w7 = emb4[(size_t)s7 * 32 + q];
        acc.x += ((w0.x + w1.x) + (w2.x + w3.x)) + ((w4.x + w5.x) + (w6.x + w7.x));
        acc.y += ((w0.y + w1.y) + (w2.y + w3.y)) + ((w4.y + w5.y) + (w6.y + w7.y));
        acc.z += ((w0.z + w1.z) + (w2.z + w3.z)) + ((w4.z + w5.z) + (w6.z + w7.z));
        acc.w += ((w0.w + w1.w) + (w2.w + w3.w)) + ((w4.w + w5.w) + (w6.w + w7.w));
    }
    for (; p < pairs; p++) {
        int s = aidx[beg + 2 * p + half];
        float4 w = emb4[(size_t)s * 32 + q];
        acc.x += w.x; acc.y += w.y; acc.z += w.z; acc.w += w.w;
    }
    if ((deg & 1) && half == 0) {
        int s = aidx[end - 1];
        float4 w = emb4[(size_t)s * 32 + q];
        acc.x += w.x; acc.y += w.y; acc.z += w.z; acc.w += w.w;
    }
    acc.x += __shfl_down(acc.x, 32, 64);
    acc.y += __shfl_down(acc.y, 32, 64);
    acc.z += __shfl_down(acc.z, 32, 64);
    acc.w += __shfl_down(acc.w, 32, 64);
    if (half == 0) {
        float sc = 1.0f / (float)(deg + 1);
        x4[(size_t)v * 32 + q] = make_float4(acc.x * sc, acc.y * sc, acc.z * sc, acc.w * sc);
    }
}

// ---------- layers 2-3 aggregation from fp16 h -----------------------------
// 4 groups of 16 lanes; each group covers one full 256B row per instruction.
union H16Chunk { float4 f4; __half2 h2[4]; };

__global__ __launch_bounds__(256) void k_agg16(
    const float4* __restrict__ h16v4, const int* __restrict__ row_ptr,
    const int* __restrict__ eidx, float4* __restrict__ x4, int n) {
    int v = blockIdx.x * 4 + (threadIdx.x >> 6);
    int lane = threadIdx.x & 63;
    int g = lane >> 4;           // group 0..3
    int q = lane & 15;           // 16B chunk within 256B row
    int beg = row_ptr[v], end = row_ptr[v + 1];
    int deg = end - beg;
    float acc[8] = {};

    #define ACCUM(raw) do { H16Chunk u; u.f4 = (raw);                          \
        float2 t0 = __half22float2(u.h2[0]); acc[0] += t0.x; acc[1] += t0.y;   \
        float2 t1 = __half22float2(u.h2[1]); acc[2] += t1.x; acc[3] += t1.y;   \
        float2 t2 = __half22float2(u.h2[2]); acc[4] += t2.x; acc[5] += t2.y;   \
        float2 t3 = __half22float2(u.h2[3]); acc[6] += t3.x; acc[7] += t3.y; } while (0)

    if (g == 0) ACCUM(h16v4[(size_t)v * 16 + q]);        // self term once

    int quads = deg >> 2;
    int p = 0;
    for (; p + 8 <= quads; p += 8) {
        int eb = beg + 4 * p + g;
        int s0 = eidx[eb +  0], s1 = eidx[eb +  4], s2 = eidx[eb +  8], s3 = eidx[eb + 12];
        int s4 = eidx[eb + 16], s5 = eidx[eb + 20], s6 = eidx[eb + 24], s7 = eidx[eb + 28];
        float4 r0 = h16v4[(size_t)s0 * 16 + q], r1 = h16v4[(size_t)s1 * 16 + q];
        float4 r2 = h16v4[(size_t)s2 * 16 + q], r3 = h16v4[(size_t)s3 * 16 + q];
        float4 r4 = h16v4[(size_t)s4 * 16 + q], r5 = h16v4[(size_t)s5 * 16 + q];
        float4 r6 = h16v4[(size_t)s6 * 16 + q], r7 = h16v4[(size_t)s7 * 16 + q];
        ACCUM(r0); ACCUM(r1); ACCUM(r2); ACCUM(r3);
        ACCUM(r4); ACCUM(r5); ACCUM(r6); ACCUM(r7);
    }
    for (; p < quads; p++) ACCUM(h16v4[(size_t)eidx[beg + 4 * p + g] * 16 + q]);
    int tail = deg & 3;
    if (g < tail) ACCUM(h16v4[(size_t)eidx[beg + 4 * quads + g] * 16 + q]);
    #undef ACCUM

    #pragma unroll
    for (int j = 0; j < 8; j++) {
        acc[j] += __shfl_down(acc[j], 16, 64);   // g0+=g1, g2+=g3
        acc[j] += __shfl_down(acc[j], 32, 64);   // g0+=g2
    }
    if (g == 0) {
        float sc = 1.0f / (float)(deg + 1);
        x4[(size_t)v * 32 + 2 * q]     = make_float4(acc[0] * sc, acc[1] * sc, acc[2] * sc, acc[3] * sc);
        x4[(size_t)v * 32 + 2 * q + 1] = make_float4(acc[4] * sc, acc[5] * sc, acc[6] * sc, acc[7] * sc);
    }
}

// ---------- relu(x @ W + b) -> fp32 out32 OR fp16 out16, persistent --------
// 256 blocks x 256 threads; W staged once; 128-row tiles; 8x8 micro-tile.
__global__ __launch_bounds__(256) void k_gemm(
    const float* __restrict__ x, const float* __restrict__ W,
    const float* __restrict__ bias, float* __restrict__ out32,
    __half* __restrict__ out16, int n, int ntiles) {
    __shared__ float Wl[128 * 128];
    __shared__ float Xs[128 * 132];  // X^T: Xs[k*132 + r]
    int tid = threadIdx.x;

    const float4* W4 = (const float4*)W;
    float4* Wl4 = (float4*)Wl;
    #pragma unroll
    for (int i = 0; i < 16; i++) Wl4[tid + i * 256] = W4[tid + i * 256];

    int c0 = (tid & 15) * 8;         // 0,8,..,120
    int r0 = (tid >> 4) * 8;         // 0,8,..,120
    int sr = tid >> 1;               // staging row 0..127
    int sq = (tid & 1) * 16;         // staging float4 base 0 or 16
    const float4* x4p = (const float4*)x;

    float4 pf[16];
    int tile = blockIdx.x;
    if (tile < ntiles) {
        int grow = tile * 128 + sr;
        if (grow < n) {
            #pragma unroll
            for (int j = 0; j < 16; j++) pf[j] = x4p[(size_t)grow * 32 + sq + j];
        }
    }
    float4 bv0 = *(const float4*)&bias[c0];
    float4 bv1 = *(const float4*)&bias[c0 + 4];

    for (; tile < ntiles; tile += gridDim.x) {
        __syncthreads();
        {
            int grow = tile * 128 + sr;
            if (grow < n) {
                #pragma unroll
                for (int j = 0; j < 16; j++) {
                    int q = sq + j;
                    Xs[(q * 4 + 0) * 132 + sr] = pf[j].x;
                    Xs[(q * 4 + 1) * 132 + sr] = pf[j].y;
                    Xs[(q * 4 + 2) * 132 + sr] = pf[j].z;
                    Xs[(q * 4 + 3) * 132 + sr] = pf[j].w;
                }
            }
        }
        __syncthreads();

        int ntile = tile + gridDim.x;
        if (ntile < ntiles) {
            int grow = ntile * 128 + sr;
            if (grow < n) {
                #pragma unroll
                for (int j = 0; j < 16; j++) pf[j] = x4p[(size_t)grow * 32 + sq + j];
            }
        }

        float acc[8][8] = {};
        #pragma unroll 2
        for (int k = 0; k < 128; k++) {
            float4 xa = *(const float4*)&Xs[k * 132 + r0];
            float4 xb = *(const float4*)&Xs[k * 132 + r0 + 4];
            float4 wa = *(const float4*)&Wl[k * 128 + c0];
            float4 wb = *(const float4*)&Wl[k * 128 + c0 + 4];
            float xr[8] = {xa.x, xa.y, xa.z, xa.w, xb.x, xb.y, xb.z, xb.w};
            float wc[8] = {wa.x, wa.y, wa.z, wa.w, wb.x, wb.y, wb.z, wb.w};
            #pragma unroll
            for (int i = 0; i < 8; i++)
                #pragma unroll
                for (int j = 0; j < 8; j++)
                    acc[i][j] += xr[i] * wc[j];
        }

        int row0 = tile * 128;
        #pragma unroll
        for (int i = 0; i < 8; i++) {
            int r = row0 + r0 + i;
            if (r < n) {
                float o[8];
                o[0] = fmaxf(acc[i][0] + bv0.x, 0.f);
                o[1] = fmaxf(acc[i][1] + bv0.y, 0.f);
                o[2] = fmaxf(acc[i][2] + bv0.z, 0.f);
                o[3] = fmaxf(acc[i][3] + bv0.w, 0.f);
                o[4] = fmaxf(acc[i][4] + bv1.x, 0.f);
                o[5] = fmaxf(acc[i][5] + bv1.y, 0.f);
                o[6] = fmaxf(acc[i][6] + bv1.z, 0.f);
                o[7] = fmaxf(acc[i][7] + bv1.w, 0.f);
                if (out16) {
                    H16Chunk u;
                    u.h2[0] = __floats2half2_rn(o[0], o[1]);
                    u.h2[1] = __floats2half2_rn(o[2], o[3]);
                    u.h2[2] = __floats2half2_rn(o[4], o[5]);
                    u.h2[3] = __floats2half2_rn(o[6], o[7]);
                    *(float4*)&out16[(size_t)r * 128 + c0] = u.f4;
                } else {
                    *(float4*)&out32[(size_t)r * 128 + c0]     = make_float4(o[0], o[1], o[2], o[3]);
                    *(float4*)&out32[(size_t)r * 128 + c0 + 4] = make_float4(o[4], o[5], o[6], o[7]);
                }
            }
        }
    }
}

extern "C" void kernel_launch(void* const* d_in, const int* in_sizes, int n_in,
                              void* d_out, int out_size, void* d_ws, size_t ws_size,
                              hipStream_t stream) {
    const int*   ann = (const int*)d_in[0];
    const int*   src = (const int*)d_in[1];
    const int*   dst = (const int*)d_in[2];
    const float* emb = (const float*)d_in[3];
    const float* Ws  = (const float*)d_in[4];
    const float* bs  = (const float*)d_in[5];
    float* out = (float*)d_out;

    const int N = in_sizes[0];   // 100000
    const int E = in_sizes[1];   // 1600000
    const int NB = (N + 255) / 256;        // 391
    const int NT = (N + 127) / 128;        // 782 row tiles

    // ws: deg/cur [N] | row_ptr [N+1] | bsum [512] | eidx [E] | aidx [E]
    //     | x32 [N*D f32] | h16 [N*D f16]   (~90.4 MB)
    int* deg     = (int*)d_ws;
    int* row_ptr = deg + ((N + 3) & ~3);
    int* bsum    = row_ptr + ((N + 1 + 3) & ~3);
    int* eidx    = bsum + 512;
    int* aidx    = eidx + ((E + 3) & ~3);
    float*  x32  = (float*)(aidx + ((E + 3) & ~3));
    __half* h16  = (__half*)(x32 + (size_t)N * D);

    // --- CSR build (once; reused by all 3 layers) ---
    hipMemsetAsync(deg, 0, (size_t)N * sizeof(int), stream);
    k_count<<<(E + 255) / 256, 256, 0, stream>>>(dst, deg, E);
    k_bsum<<<NB, 256, 0, stream>>>(deg, bsum, N);
    k_scanb<<<1, 512, 0, stream>>>(bsum, NB, row_ptr, N, E);
    k_scan_local<<<NB, 256, 0, stream>>>(deg, bsum, row_ptr, N);
    hipMemsetAsync(deg, 0, (size_t)N * sizeof(int), stream);   // reuse as cursor
    k_fill<<<(E + 255) / 256, 256, 0, stream>>>(src, dst, ann, row_ptr, deg, eidx, aidx, E);

    // --- layer 1: agg from emb (fp32) -> x32; gemm -> h16 ---
    k_agg_emb<<<N / 4, 256, 0, stream>>>((const float4*)emb, ann, row_ptr, aidx,
                                         (float4*)x32, N);
    k_gemm<<<256, 256, 0, stream>>>(x32, Ws, bs, nullptr, h16, N, NT);

    // --- layer 2: agg from h16 -> x32; gemm -> h16 (h1 dead after agg) ---
    k_agg16<<<N / 4, 256, 0, stream>>>((const float4*)h16, row_ptr, eidx,
                                       (float4*)x32, N);
    k_gemm<<<256, 256, 0, stream>>>(x32, Ws + (size_t)D * D, bs + D, nullptr, h16, N, NT);

    // --- layer 3: agg from h16 -> x32; gemm -> out (fp32) ---
    k_agg16<<<N / 4, 256, 0, stream>>>((const float4*)h16, row_ptr, eidx,
                                       (float4*)x32, N);
    k_gemm<<<256, 256, 0, stream>>>(x32, Ws + (size_t)2 * D * D, bs + 2 * D, out, nullptr, N, NT);
}

// Round 7
// 655.267 us; speedup vs baseline: 12.9563x; 1.0800x over previous
//
#include <hip/hip_runtime.h>
#include <hip/hip_fp16.h>

// Graph_NN: 3-layer SAGE (gcn aggregator), N=100000, E=1600000, D=128, fp32.
// R7: (a) k_fill writes one packed int2 (src, ann[src]) per edge -> half the
//     scattered-write line traffic (was 155 MB / 102 us, two 4B streams).
// (b) layer 1 projects-then-aggregates: embW = emb @ W1 (V=5000-row GEMM,
//     ~2 us) then k_aggW sums embW rows (L2-resident 2.56 MB) with fused
//     inv*sum + b1, relu, fp16 epilogue -> deletes one N-row GEMM + the
//     entire x32 round-trip for layer 1. fp32 reorder error ~1e-6.
// Layers 2-3 unchanged: agg16 (fp16 rows, ~3.3 TB/s random ceiling) -> x32
// -> gemm -> fp16.

#define D 128

// ---------- CSR build ----------
__global__ void k_count(const int* __restrict__ dst, int* __restrict__ deg, int E) {
    int e = blockIdx.x * blockDim.x + threadIdx.x;
    if (e < E) atomicAdd(&deg[dst[e]], 1);
}

__global__ void k_bsum(const int* __restrict__ deg, int* __restrict__ bsum, int n) {
    __shared__ int s[256];
    int t = threadIdx.x, i = blockIdx.x * 256 + t;
    s[t] = (i < n) ? deg[i] : 0;
    __syncthreads();
    for (int off = 128; off > 0; off >>= 1) { if (t < off) s[t] += s[t + off]; __syncthreads(); }
    if (t == 0) bsum[blockIdx.x] = s[0];
}

__global__ void k_scanb(int* __restrict__ bsum, int nb, int* __restrict__ row_ptr, int N, int E) {
    __shared__ int s[512];
    int t = threadIdx.x;
    int v = (t < nb) ? bsum[t] : 0;
    s[t] = v;
    __syncthreads();
    for (int off = 1; off < 512; off <<= 1) {
        int x = (t >= off) ? s[t - off] : 0;
        __syncthreads();
        s[t] += x;
        __syncthreads();
    }
    if (t < nb) bsum[t] = s[t] - v;          // exclusive prefix
    if (t == 0) row_ptr[N] = E;
}

__global__ void k_scan_local(const int* __restrict__ deg, const int* __restrict__ bpre,
                             int* __restrict__ row_ptr, int n) {
    __shared__ int s[256];
    int t = threadIdx.x, i = blockIdx.x * 256 + t;
    int v = (i < n) ? deg[i] : 0;
    s[t] = v;
    __syncthreads();
    for (int off = 1; off < 256; off <<= 1) {
        int x = (t >= off) ? s[t - off] : 0;
        __syncthreads();
        s[t] += x;
        __syncthreads();
    }
    if (i < n) row_ptr[i] = bpre[blockIdx.x] + s[t] - v;   // exclusive
}

// fill eal[pos] = (src, ann[src]) grouped by dst — single 8B scattered write
__global__ void k_fill(const int* __restrict__ src, const int* __restrict__ dst,
                       const int* __restrict__ ann, const int* __restrict__ row_ptr,
                       int* __restrict__ cur, int2* __restrict__ eal, int E) {
    int e = blockIdx.x * blockDim.x + threadIdx.x;
    if (e >= E) return;
    int d = dst[e];
    int s = src[e];
    int pos = atomicAdd(&cur[d], 1);
    eal[row_ptr[d] + pos] = make_int2(s, ann[s]);
}

// ---------- small plain GEMM: out = x @ W (no bias/relu), V rows ----------
__global__ __launch_bounds__(256) void k_gemm_plain(
    const float* __restrict__ x, const float* __restrict__ W,
    float* __restrict__ out, int n, int ntiles) {
    __shared__ float Wl[128 * 128];
    __shared__ float Xs[128 * 132];
    int tid = threadIdx.x;

    const float4* W4 = (const float4*)W;
    float4* Wl4 = (float4*)Wl;
    #pragma unroll
    for (int i = 0; i < 16; i++) Wl4[tid + i * 256] = W4[tid + i * 256];

    int c0 = (tid & 15) * 8;
    int r0 = (tid >> 4) * 8;
    int sr = tid >> 1;
    int sq = (tid & 1) * 16;
    const float4* x4p = (const float4*)x;

    for (int tile = blockIdx.x; tile < ntiles; tile += gridDim.x) {
        __syncthreads();
        {
            int grow = tile * 128 + sr;
            if (grow < n) {
                #pragma unroll
                for (int j = 0; j < 16; j++) {
                    int q = sq + j;
                    float4 v = x4p[(size_t)grow * 32 + q];
                    Xs[(q * 4 + 0) * 132 + sr] = v.x;
                    Xs[(q * 4 + 1) * 132 + sr] = v.y;
                    Xs[(q * 4 + 2) * 132 + sr] = v.z;
                    Xs[(q * 4 + 3) * 132 + sr] = v.w;
                }
            }
        }
        __syncthreads();

        float acc[8][8] = {};
        #pragma unroll 2
        for (int k = 0; k < 128; k++) {
            float4 xa = *(const float4*)&Xs[k * 132 + r0];
            float4 xb = *(const float4*)&Xs[k * 132 + r0 + 4];
            float4 wa = *(const float4*)&Wl[k * 128 + c0];
            float4 wb = *(const float4*)&Wl[k * 128 + c0 + 4];
            float xr[8] = {xa.x, xa.y, xa.z, xa.w, xb.x, xb.y, xb.z, xb.w};
            float wc[8] = {wa.x, wa.y, wa.z, wa.w, wb.x, wb.y, wb.z, wb.w};
            #pragma unroll
            for (int i = 0; i < 8; i++)
                #pragma unroll
                for (int j = 0; j < 8; j++)
                    acc[i][j] += xr[i] * wc[j];
        }

        int row0 = tile * 128;
        #pragma unroll
        for (int i = 0; i < 8; i++) {
            int r = row0 + r0 + i;
            if (r < n) {
                *(float4*)&out[(size_t)r * 128 + c0]     = make_float4(acc[i][0], acc[i][1], acc[i][2], acc[i][3]);
                *(float4*)&out[(size_t)r * 128 + c0 + 4] = make_float4(acc[i][4], acc[i][5], acc[i][6], acc[i][7]);
            }
        }
    }
}

// ---------- layer-1 fused agg over embW (L2-resident) -> relu -> fp16 ------
// h1[v] = relu( inv * (embW[ann[v]] + sum_u embW[ann[u]]) + b1 ), fp16 out
union H16Half { float2 f2; __half2 h2[2]; };

__global__ __launch_bounds__(256) void k_aggW(
    const float4* __restrict__ eW4, const int* __restrict__ ann,
    const int* __restrict__ row_ptr, const int2* __restrict__ eal,
    const float4* __restrict__ bias4, __half* __restrict__ h16, int n) {
    int v = blockIdx.x * 4 + (threadIdx.x >> 6);
    int lane = threadIdx.x & 63;
    int half = lane >> 5;
    int q = lane & 31;
    int beg = row_ptr[v], end = row_ptr[v + 1];
    int deg = end - beg;
    float4 acc = make_float4(0.f, 0.f, 0.f, 0.f);
    if (half == 0) acc = eW4[(size_t)ann[v] * 32 + q];   // self term once

    int pairs = deg >> 1;
    int p = 0;
    for (; p + 8 <= pairs; p += 8) {
        int eb = beg + 2 * p + half;
        int s0 = eal[eb +  0].y, s1 = eal[eb +  2].y, s2 = eal[eb +  4].y, s3 = eal[eb +  6].y;
        int s4 = eal[eb +  8].y, s5 = eal[eb + 10].y, s6 = eal[eb + 12].y, s7 = eal[eb + 14].y;
        float4 w0 = eW4[(size_t)s0 * 32 + q], w1 = eW4[(size_t)s1 * 32 + q];
        float4 w2 = eW4[(size_t)s2 * 32 + q], w3 = eW4[(size_t)s3 * 32 + q];
        float4 w4 = eW4[(size_t)s4 * 32 + q], w5 = eW4[(size_t)s5 * 32 + q];
        float4 w6 = eW4[(size_t)s6 * 32 + q], w7 = eW4[(size_t)s7 * 32 + q];
        acc.x += ((w0.x + w1.x) + (w2.x + w3.x)) + ((w4.x + w5.x) + (w6.x + w7.x));
        acc.y += ((w0.y + w1.y) + (w2.y + w3.y)) + ((w4.y + w5.y) + (w6.y + w7.y));
        acc.z += ((w0.z + w1.z) + (w2.z + w3.z)) + ((w4.z + w5.z) + (w6.z + w7.z));
        acc.w += ((w0.w + w1.w) + (w2.w + w3.w)) + ((w4.w + w5.w) + (w6.w + w7.w));
    }
    for (; p < pairs; p++) {
        int s = eal[beg + 2 * p + half].y;
        float4 w = eW4[(size_t)s * 32 + q];
        acc.x += w.x; acc.y += w.y; acc.z += w.z; acc.w += w.w;
    }
    if ((deg & 1) && half == 0) {
        int s = eal[end - 1].y;
        float4 w = eW4[(size_t)s * 32 + q];
        acc.x += w.x; acc.y += w.y; acc.z += w.z; acc.w += w.w;
    }
    acc.x += __shfl_down(acc.x, 32, 64);
    acc.y += __shfl_down(acc.y, 32, 64);
    acc.z += __shfl_down(acc.z, 32, 64);
    acc.w += __shfl_down(acc.w, 32, 64);
    if (half == 0) {
        float sc = 1.0f / (float)(deg + 1);
        float4 bv = bias4[q];
        float o0 = fmaxf(acc.x * sc + bv.x, 0.f);
        float o1 = fmaxf(acc.y * sc + bv.y, 0.f);
        float o2 = fmaxf(acc.z * sc + bv.z, 0.f);
        float o3 = fmaxf(acc.w * sc + bv.w, 0.f);
        H16Half u;
        u.h2[0] = __floats2half2_rn(o0, o1);
        u.h2[1] = __floats2half2_rn(o2, o3);
        *(float2*)&h16[(size_t)v * 128 + q * 4] = u.f2;
    }
}

// ---------- layers 2-3 aggregation from fp16 h -----------------------------
// 4 groups of 16 lanes; each group covers one full 256B row per instruction.
union H16Chunk { float4 f4; __half2 h2[4]; };

__global__ __launch_bounds__(256) void k_agg16(
    const float4* __restrict__ h16v4, const int* __restrict__ row_ptr,
    const int2* __restrict__ eal, float4* __restrict__ x4, int n) {
    int v = blockIdx.x * 4 + (threadIdx.x >> 6);
    int lane = threadIdx.x & 63;
    int g = lane >> 4;           // group 0..3
    int q = lane & 15;           // 16B chunk within 256B row
    int beg = row_ptr[v], end = row_ptr[v + 1];
    int deg = end - beg;
    float acc[8] = {};

    #define ACCUM(raw) do { H16Chunk u; u.f4 = (raw);                          \
        float2 t0 = __half22float2(u.h2[0]); acc[0] += t0.x; acc[1] += t0.y;   \
        float2 t1 = __half22float2(u.h2[1]); acc[2] += t1.x; acc[3] += t1.y;   \
        float2 t2 = __half22float2(u.h2[2]); acc[4] += t2.x; acc[5] += t2.y;   \
        float2 t3 = __half22float2(u.h2[3]); acc[6] += t3.x; acc[7] += t3.y; } while (0)

    if (g == 0) ACCUM(h16v4[(size_t)v * 16 + q]);        // self term once

    int quads = deg >> 2;
    int p = 0;
    for (; p + 8 <= quads; p += 8) {
        int eb = beg + 4 * p + g;
        int s0 = eal[eb +  0].x, s1 = eal[eb +  4].x, s2 = eal[eb +  8].x, s3 = eal[eb + 12].x;
        int s4 = eal[eb + 16].x, s5 = eal[eb + 20].x, s6 = eal[eb + 24].x, s7 = eal[eb + 28].x;
        float4 r0 = h16v4[(size_t)s0 * 16 + q], r1 = h16v4[(size_t)s1 * 16 + q];
        float4 r2 = h16v4[(size_t)s2 * 16 + q], r3 = h16v4[(size_t)s3 * 16 + q];
        float4 r4 = h16v4[(size_t)s4 * 16 + q], r5 = h16v4[(size_t)s5 * 16 + q];
        float4 r6 = h16v4[(size_t)s6 * 16 + q], r7 = h16v4[(size_t)s7 * 16 + q];
        ACCUM(r0); ACCUM(r1); ACCUM(r2); ACCUM(r3);
        ACCUM(r4); ACCUM(r5); ACCUM(r6); ACCUM(r7);
    }
    for (; p < quads; p++) ACCUM(h16v4[(size_t)eal[beg + 4 * p + g].x * 16 + q]);
    int tail = deg & 3;
    if (g < tail) ACCUM(h16v4[(size_t)eal[beg + 4 * quads + g].x * 16 + q]);
    #undef ACCUM

    #pragma unroll
    for (int j = 0; j < 8; j++) {
        acc[j] += __shfl_down(acc[j], 16, 64);   // g0+=g1, g2+=g3
        acc[j] += __shfl_down(acc[j], 32, 64);   // g0+=g2
    }
    if (g == 0) {
        float sc = 1.0f / (float)(deg + 1);
        x4[(size_t)v * 32 + 2 * q]     = make_float4(acc[0] * sc, acc[1] * sc, acc[2] * sc, acc[3] * sc);
        x4[(size_t)v * 32 + 2 * q + 1] = make_float4(acc[4] * sc, acc[5] * sc, acc[6] * sc, acc[7] * sc);
    }
}

// ---------- relu(x @ W + b) -> fp32 out32 OR fp16 out16, persistent --------
__global__ __launch_bounds__(256) void k_gemm(
    const float* __restrict__ x, const float* __restrict__ W,
    const float* __restrict__ bias, float* __restrict__ out32,
    __half* __restrict__ out16, int n, int ntiles) {
    __shared__ float Wl[128 * 128];
    __shared__ float Xs[128 * 132];
    int tid = threadIdx.x;

    const float4* W4 = (const float4*)W;
    float4* Wl4 = (float4*)Wl;
    #pragma unroll
    for (int i = 0; i < 16; i++) Wl4[tid + i * 256] = W4[tid + i * 256];

    int c0 = (tid & 15) * 8;
    int r0 = (tid >> 4) * 8;
    int sr = tid >> 1;
    int sq = (tid & 1) * 16;
    const float4* x4p = (const float4*)x;

    float4 pf[16];
    int tile = blockIdx.x;
    if (tile < ntiles) {
        int grow = tile * 128 + sr;
        if (grow < n) {
            #pragma unroll
            for (int j = 0; j < 16; j++) pf[j] = x4p[(size_t)grow * 32 + sq + j];
        }
    }
    float4 bv0 = *(const float4*)&bias[c0];
    float4 bv1 = *(const float4*)&bias[c0 + 4];

    for (; tile < ntiles; tile += gridDim.x) {
        __syncthreads();
        {
            int grow = tile * 128 + sr;
            if (grow < n) {
                #pragma unroll
                for (int j = 0; j < 16; j++) {
                    int q = sq + j;
                    Xs[(q * 4 + 0) * 132 + sr] = pf[j].x;
                    Xs[(q * 4 + 1) * 132 + sr] = pf[j].y;
                    Xs[(q * 4 + 2) * 132 + sr] = pf[j].z;
                    Xs[(q * 4 + 3) * 132 + sr] = pf[j].w;
                }
            }
        }
        __syncthreads();

        int ntile = tile + gridDim.x;
        if (ntile < ntiles) {
            int grow = ntile * 128 + sr;
            if (grow < n) {
                #pragma unroll
                for (int j = 0; j < 16; j++) pf[j] = x4p[(size_t)grow * 32 + sq + j];
            }
        }

        float acc[8][8] = {};
        #pragma unroll 2
        for (int k = 0; k < 128; k++) {
            float4 xa = *(const float4*)&Xs[k * 132 + r0];
            float4 xb = *(const float4*)&Xs[k * 132 + r0 + 4];
            float4 wa = *(const float4*)&Wl[k * 128 + c0];
            float4 wb = *(const float4*)&Wl[k * 128 + c0 + 4];
            float xr[8] = {xa.x, xa.y, xa.z, xa.w, xb.x, xb.y, xb.z, xb.w};
            float wc[8] = {wa.x, wa.y, wa.z, wa.w, wb.x, wb.y, wb.z, wb.w};
            #pragma unroll
            for (int i = 0; i < 8; i++)
                #pragma unroll
                for (int j = 0; j < 8; j++)
                    acc[i][j] += xr[i] * wc[j];
        }

        int row0 = tile * 128;
        #pragma unroll
        for (int i = 0; i < 8; i++) {
            int r = row0 + r0 + i;
            if (r < n) {
                float o[8];
                o[0] = fmaxf(acc[i][0] + bv0.x, 0.f);
                o[1] = fmaxf(acc[i][1] + bv0.y, 0.f);
                o[2] = fmaxf(acc[i][2] + bv0.z, 0.f);
                o[3] = fmaxf(acc[i][3] + bv0.w, 0.f);
                o[4] = fmaxf(acc[i][4] + bv1.x, 0.f);
                o[5] = fmaxf(acc[i][5] + bv1.y, 0.f);
                o[6] = fmaxf(acc[i][6] + bv1.z, 0.f);
                o[7] = fmaxf(acc[i][7] + bv1.w, 0.f);
                if (out16) {
                    H16Chunk u;
                    u.h2[0] = __floats2half2_rn(o[0], o[1]);
                    u.h2[1] = __floats2half2_rn(o[2], o[3]);
                    u.h2[2] = __floats2half2_rn(o[4], o[5]);
                    u.h2[3] = __floats2half2_rn(o[6], o[7]);
                    *(float4*)&out16[(size_t)r * 128 + c0] = u.f4;
                } else {
                    *(float4*)&out32[(size_t)r * 128 + c0]     = make_float4(o[0], o[1], o[2], o[3]);
                    *(float4*)&out32[(size_t)r * 128 + c0 + 4] = make_float4(o[4], o[5], o[6], o[7]);
                }
            }
        }
    }
}

extern "C" void kernel_launch(void* const* d_in, const int* in_sizes, int n_in,
                              void* d_out, int out_size, void* d_ws, size_t ws_size,
                              hipStream_t stream) {
    const int*   ann = (const int*)d_in[0];
    const int*   src = (const int*)d_in[1];
    const int*   dst = (const int*)d_in[2];
    const float* emb = (const float*)d_in[3];
    const float* Ws  = (const float*)d_in[4];
    const float* bs  = (const float*)d_in[5];
    float* out = (float*)d_out;

    const int N = in_sizes[0];          // 100000
    const int E = in_sizes[1];          // 1600000
    const int V = in_sizes[3] / D;      // 5000
    const int NB  = (N + 255) / 256;    // 391
    const int NT  = (N + 127) / 128;    // 782
    const int NTV = (V + 127) / 128;    // 40

    // ws: deg/cur [N] | row_ptr [N+1] | bsum [512] | eal [int2 E]
    //     | x32 [N*D f32] | h16 [N*D f16] | embW [V*D f32]    (~93 MB)
    int*  deg     = (int*)d_ws;
    int*  row_ptr = deg + ((N + 3) & ~3);
    int*  bsum    = row_ptr + ((N + 1 + 3) & ~3);
    int2* eal     = (int2*)(bsum + 512);
    float*  x32   = (float*)(eal + E);
    __half* h16   = (__half*)(x32 + (size_t)N * D);
    float*  embW  = (float*)(h16 + (size_t)N * D);

    // --- embW = emb @ W1 (tiny; independent of CSR) ---
    k_gemm_plain<<<NTV, 256, 0, stream>>>(emb, Ws, embW, V, NTV);

    // --- CSR build (once; reused by all 3 layers) ---
    hipMemsetAsync(deg, 0, (size_t)N * sizeof(int), stream);
    k_count<<<(E + 255) / 256, 256, 0, stream>>>(dst, deg, E);
    k_bsum<<<NB, 256, 0, stream>>>(deg, bsum, N);
    k_scanb<<<1, 512, 0, stream>>>(bsum, NB, row_ptr, N, E);
    k_scan_local<<<NB, 256, 0, stream>>>(deg, bsum, row_ptr, N);
    hipMemsetAsync(deg, 0, (size_t)N * sizeof(int), stream);   // reuse as cursor
    k_fill<<<(E + 255) / 256, 256, 0, stream>>>(src, dst, ann, row_ptr, deg, eal, E);

    // --- layer 1 (fused): aggregate embW rows, inv*sum + b1, relu -> h16 ---
    k_aggW<<<N / 4, 256, 0, stream>>>((const float4*)embW, ann, row_ptr, eal,
                                      (const float4*)bs, h16, N);

    // --- layer 2: agg from h16 -> x32; gemm -> h16 ---
    k_agg16<<<N / 4, 256, 0, stream>>>((const float4*)h16, row_ptr, eal,
                                       (float4*)x32, N);
    k_gemm<<<256, 256, 0, stream>>>(x32, Ws + (size_t)D * D, bs + D, nullptr, h16, N, NT);

    // --- layer 3: agg from h16 -> x32; gemm -> out (fp32) ---
    k_agg16<<<N / 4, 256, 0, stream>>>((const float4*)h16, row_ptr, eal,
                                       (float4*)x32, N);
    k_gemm<<<256, 256, 0, stream>>>(x32, Ws + (size_t)2 * D * D, bs + 2 * D, out, nullptr, N, NT);
}